// Round 2
// baseline (529.233 us; speedup 1.0000x reference)
//
#include <hip/hip_runtime.h>

#define B_ 8
#define N_ 8192
#define E_ 1024
#define D_ 256
#define ROWS (B_ * N_)      // 65536
#define K2 512              // 2*D
#define GRID_F 512
#define RPB (ROWS / GRID_F) // 128 rows per fused block

__global__ __launch_bounds__(256) void scatter_kernel(
    const float* __restrict__ obs, const int* __restrict__ idx,
    float* __restrict__ sums, float* __restrict__ cnt) {
    const int row = blockIdx.x;        // one row per 256-thread block
    const int t   = threadIdx.x;       // d index
    const int b   = row >> 13;         // / N_
    const int e   = idx[row];
    const int be  = (b << 10) + e;
    const float v = obs[(row << 8) + t];
    atomicAdd(&sums[(be << 8) + t], v);
    if (t == 0) atomicAdd(&cnt[be], 1.0f);
}

__global__ __launch_bounds__(256, 2) void fused_kernel(
    const float* __restrict__ obs, const float* __restrict__ mask,
    const int* __restrict__ idx, const float* __restrict__ wm,
    const float* __restrict__ bmp, const float* __restrict__ we,
    const float* __restrict__ bep, const float* __restrict__ sums,
    const float* __restrict__ cnt, float* __restrict__ out) {

    const int t = threadIdx.x;
    const int w = t >> 6;          // wave id = K-chunk id (0..3)
    const int j = t & 63;          // lane = output column (0..63)
    const int kbase = w << 7;      // w*128

    // w_e[j][kbase .. kbase+127] resident in registers (read from HBM once per block)
    float wreg[128];
#pragma unroll
    for (int i = 0; i < 128; i += 4) {
        const float4 v = *(const float4*)(we + j * K2 + kbase + i);
        wreg[i + 0] = v.x; wreg[i + 1] = v.y;
        wreg[i + 2] = v.z; wreg[i + 3] = v.w;
    }
    const float wm1 = wm[kbase + j];
    const float wm2 = wm[kbase + 64 + j];
    const float bm  = bmp[0];
    const float be  = (t < 64) ? bep[t] : 0.0f;

    __shared__ float partial[4][64];
    __shared__ float wsum[4];

    float* out_g = out;            // (B,N)
    float* out_e = out + ROWS;     // (B,N,64)

    const int row0 = blockIdx.x * RPB;
    for (int r = 0; r < RPB; ++r) {
        const int row   = row0 + r;
        const int b     = row >> 13;
        const int e     = idx[row];                 // wave-uniform
        const int bei   = (b << 10) + e;
        const float inv = 1.0f / fmaxf(cnt[bei], 1.0f);
        const int obase = row << 8;                 // row*256
        const int sbase = bei << 8;

        // ---- membrane partial: lane j covers k = kbase+j and kbase+64+j ----
        float x1, x2;
        if (w < 2) {
            x1 = obs[obase + kbase + j];
            x2 = obs[obase + kbase + 64 + j];
        } else {
            const int d1 = kbase - 256 + j;
            x1 = obs[obase + d1]      - sums[sbase + d1]      * inv;
            x2 = obs[obase + d1 + 64] - sums[sbase + d1 + 64] * inv;
        }
        float pm = fmaf(x1, wm1, x2 * wm2);
#pragma unroll
        for (int off = 1; off < 64; off <<= 1) pm += __shfl_xor(pm, off);

        // ---- e_n: lane j accumulates col j over its K-chunk (broadcast loads) ----
        float acc = 0.0f;
        if (w < 2) {
#pragma unroll
            for (int i = 0; i < 128; i += 4) {
                const float4 m4 = *(const float4*)(obs + obase + kbase + i);
                acc = fmaf(m4.x, wreg[i + 0], acc);
                acc = fmaf(m4.y, wreg[i + 1], acc);
                acc = fmaf(m4.z, wreg[i + 2], acc);
                acc = fmaf(m4.w, wreg[i + 3], acc);
            }
        } else {
            const int dbase = kbase - 256;
#pragma unroll
            for (int i = 0; i < 128; i += 4) {
                const float4 o4 = *(const float4*)(obs + obase + dbase + i);
                const float4 s4 = *(const float4*)(sums + sbase + dbase + i);
                acc = fmaf(fmaf(-s4.x, inv, o4.x), wreg[i + 0], acc);
                acc = fmaf(fmaf(-s4.y, inv, o4.y), wreg[i + 1], acc);
                acc = fmaf(fmaf(-s4.z, inv, o4.z), wreg[i + 2], acc);
                acc = fmaf(fmaf(-s4.w, inv, o4.w), wreg[i + 3], acc);
            }
        }
        if (j == 0) wsum[w] = pm;
        partial[w][j] = acc;
        __syncthreads();

        if (t < 64) {
            const float m  = wsum[0] + wsum[1] + wsum[2] + wsum[3] + bm;
            const float mk = mask[row];
            const float g  = mk / (1.0f + expf(-m));             // sigmoid(m)*mask
            const float ev = (partial[0][t] + partial[1][t] + partial[2][t] +
                              partial[3][t] + be) * g * mk;
            out_e[(row << 6) + t] = ev;
            if (t == 0) out_g[row] = g;
        }
        __syncthreads();  // protect partial/wsum before next row
    }
}

extern "C" void kernel_launch(void* const* d_in, const int* in_sizes, int n_in,
                              void* d_out, int out_size, void* d_ws, size_t ws_size,
                              hipStream_t stream) {
    (void)in_sizes; (void)n_in; (void)out_size; (void)ws_size;
    const float* obs  = (const float*)d_in[0];
    const float* mask = (const float*)d_in[1];
    // d_in[2] = incidence matrix: one-hot of idx, never read (saves 268 MB of traffic)
    const int*   idx  = (const int*)d_in[3];
    const float* w_m  = (const float*)d_in[4];
    const float* b_m  = (const float*)d_in[5];
    const float* w_e  = (const float*)d_in[6];
    const float* b_e  = (const float*)d_in[7];

    float* cnt  = (float*)d_ws;                    // B*E floats
    float* sums = cnt + B_ * E_;                   // B*E*D floats

    hipMemsetAsync(d_ws, 0, (size_t)(B_ * E_ + (size_t)B_ * E_ * D_) * sizeof(float), stream);

    scatter_kernel<<<ROWS, 256, 0, stream>>>(obs, idx, sums, cnt);

    fused_kernel<<<GRID_F, 256, 0, stream>>>(obs, mask, idx, w_m, b_m, w_e, b_e,
                                             sums, cnt, (float*)d_out);
}

// Round 3
// 69.419 us; speedup vs baseline: 7.6237x; 7.6237x over previous
//
#include <hip/hip_runtime.h>

#define B_ 8
#define N_ 8192
#define E_ 1024
#define D_ 256
#define ROWS (B_ * N_)          // 65536
#define BE (B_ * E_)            // 8192
#define K2 512
#define NT 5                    // n-tiles: 64 e-cols + membrane col + pad
#define KT 16                   // k-tiles of 32

typedef float  f32x4  __attribute__((ext_vector_type(4)));
typedef __bf16 bf16x4 __attribute__((ext_vector_type(4)));
typedef __bf16 bf16x8 __attribute__((ext_vector_type(8)));

// ---- workspace layout (bytes) ----
#define CTX_OFF   0                                   // BE*D f32 mean      (8 MB)
#define WEF_OFF   (BE * D_ * 4)                       // frag-packed W bf16 (80 KB)
#define HIST_OFF  (WEF_OFF + KT * NT * 64 * 8 * 2)
#define CURS_OFF  (HIST_OFF + BE * 4)
#define ORDER_OFF (CURS_OFF + BE * 4)                 // + ROWS*4 => ~8.8 MB total

// ---------- bucket pipeline (replaces 16.7M-atomic scatter) ----------
__global__ __launch_bounds__(256) void hist_kernel(const int* __restrict__ idx,
                                                   unsigned* __restrict__ hist) {
    const int row = blockIdx.x * 256 + threadIdx.x;
    atomicAdd(&hist[((row >> 13) << 10) + idx[row]], 1u);
}

__global__ __launch_bounds__(256) void scan_kernel(const unsigned* __restrict__ hist,
                                                   unsigned* __restrict__ cursor) {
    __shared__ unsigned part[256];
    const int t = threadIdx.x;
    unsigned s = 0;
    for (int i = 0; i < 32; ++i) s += hist[t * 32 + i];
    part[t] = s;
    __syncthreads();
    if (t == 0) {
        unsigned run = 0;
        for (int i = 0; i < 256; ++i) { const unsigned v = part[i]; part[i] = run; run += v; }
    }
    __syncthreads();
    unsigned run = part[t];
    for (int i = 0; i < 32; ++i) { const unsigned v = hist[t * 32 + i]; cursor[t * 32 + i] = run; run += v; }
}

__global__ __launch_bounds__(256) void fill_kernel(const int* __restrict__ idx,
                                                   unsigned* __restrict__ cursor,
                                                   unsigned* __restrict__ order) {
    const int row = blockIdx.x * 256 + threadIdx.x;
    const int bei = ((row >> 13) << 10) + idx[row];
    order[atomicAdd(&cursor[bei], 1u)] = (unsigned)row;
}

// per-bucket gather-mean: one wave per (b,e); a wave-load covers one full obs row (1 KB)
__global__ __launch_bounds__(256) void ctx_kernel(const float* __restrict__ obs,
                                                  const unsigned* __restrict__ hist,
                                                  const unsigned* __restrict__ cursor,
                                                  const unsigned* __restrict__ order,
                                                  float* __restrict__ ctx) {
    const int bucket = blockIdx.x * 4 + (threadIdx.x >> 6);
    const int l = threadIdx.x & 63;
    const unsigned cnt = hist[bucket];
    const unsigned start = cursor[bucket] - cnt;   // cursor holds base+cnt after fill
    float4 acc = make_float4(0.f, 0.f, 0.f, 0.f);
    for (unsigned i = 0; i < cnt; ++i) {
        const unsigned row = order[start + i];
        const float4 v = *(const float4*)(obs + ((size_t)row << 8) + (l << 2));
        acc.x += v.x; acc.y += v.y; acc.z += v.z; acc.w += v.w;
    }
    const float inv = 1.f / fmaxf((float)cnt, 1.f);
    float4 m; m.x = acc.x * inv; m.y = acc.y * inv; m.z = acc.z * inv; m.w = acc.w * inv;
    *(float4*)(ctx + (bucket << 8) + (l << 2)) = m;
}

// pack W = [we(64 rows); w_m(1 row); zeros(15)] as bf16 MFMA B-fragments, frag-ordered:
// wef[((kt*NT+nt)*64 + lane)*8 + i] = W[nt*16 + (lane&15)][kt*32 + (lane>>4)*8 + i]
__global__ __launch_bounds__(256) void wef_kernel(const float* __restrict__ we,
                                                  const float* __restrict__ wm,
                                                  __bf16* __restrict__ wef) {
    const int t = blockIdx.x * 256 + threadIdx.x;
    if (t >= KT * NT * 64) return;
    const int lane = t & 63;
    const int nt = (t >> 6) % NT;
    const int kt = t / (NT * 64);
    const int r  = nt * 16 + (lane & 15);
    const int k0 = kt * 32 + (lane >> 4) * 8;
    bf16x8 v;
#pragma unroll
    for (int i = 0; i < 8; ++i) {
        const int k = k0 + i;
        const float f = (r < 64) ? we[r * K2 + k] : ((r == 64) ? wm[k] : 0.f);
        v[i] = (__bf16)f;
    }
    *(bf16x8*)(wef + (size_t)t * 8) = v;
}

// ---------- fused MFMA kernel: 4 waves/block, 32 rows/wave, no __syncthreads ----------
// LDS row layout (256 elems): elem k stored at pos = ((k>>3)&3)<<6 | ((((k>>5)^(r&7))&7)<<3 | (k&7)
//   -> ds_write_b64 (build) and ds_read_b128 (A-frags) are both bank-conflict-free.
__global__ __launch_bounds__(256, 2) void fused_kernel(
    const float* __restrict__ obs, const float* __restrict__ mask,
    const int* __restrict__ idx, const float* __restrict__ bmp,
    const float* __restrict__ bep, const float* __restrict__ ctx,
    const __bf16* __restrict__ wef, float* __restrict__ out) {

    const int tid = threadIdx.x;
    const int wid = tid >> 6;
    const int l   = tid & 63;
    const int rw0 = blockIdx.x * 128 + wid * 32;

    __shared__ __bf16 mi[4][32][256];   // 64 KB, per-wave private slices

    f32x4 acc[2][NT];
#pragma unroll
    for (int a = 0; a < 2; ++a)
#pragma unroll
        for (int b = 0; b < NT; ++b) acc[a][b] = (f32x4){0.f, 0.f, 0.f, 0.f};

    const float bm = bmp[0];
    float be4[4];
#pragma unroll
    for (int nt = 0; nt < 4; ++nt) be4[nt] = bep[nt * 16 + (l & 15)];

    const int wq = ((l >> 1) & 3) << 6;           // write window (lane covers k = 4l..4l+3)
    const int wsub = (l & 1) << 2;

    // ---- stage chunk 0: bf16(obs[:, 0:256]) ----
#pragma unroll 4
    for (int it = 0; it < 32; ++it) {
        const int row = rw0 + it;
        const float4 o = *(const float4*)(obs + ((size_t)row << 8) + (l << 2));
        bf16x4 v; v[0] = (__bf16)o.x; v[1] = (__bf16)o.y; v[2] = (__bf16)o.z; v[3] = (__bf16)o.w;
        const int pos = wq | ((((l >> 3) ^ it) & 7) << 3) | wsub;
        *(bf16x4*)&mi[wid][it][pos] = v;
    }

    // ---- MFMA over chunk 0 (global k-tiles 0..7) ----
#pragma unroll
    for (int kt = 0; kt < 8; ++kt) {
        const int apos = ((l >> 4) << 6) | (((kt ^ l) & 7) << 3);
        const bf16x8 a0 = *(const bf16x8*)&mi[wid][(l & 15)][apos];
        const bf16x8 a1 = *(const bf16x8*)&mi[wid][16 + (l & 15)][apos];
#pragma unroll
        for (int nt = 0; nt < NT; ++nt) {
            const bf16x8 bb = *(const bf16x8*)(wef + (size_t)(((kt * NT + nt) << 6) + l) * 8);
            acc[0][nt] = __builtin_amdgcn_mfma_f32_16x16x32_bf16(a0, bb, acc[0][nt], 0, 0, 0);
            acc[1][nt] = __builtin_amdgcn_mfma_f32_16x16x32_bf16(a1, bb, acc[1][nt], 0, 0, 0);
        }
    }

    // ---- stage chunk 1 in place: bf16(obs) - ctx (re-reads own staged obs, no HBM re-read) ----
#pragma unroll 4
    for (int it = 0; it < 32; ++it) {
        const int row = rw0 + it;
        const int bei = ((row >> 13) << 10) + idx[row];
        const int pos = wq | ((((l >> 3) ^ it) & 7) << 3) | wsub;
        const bf16x4 ov = *(const bf16x4*)&mi[wid][it][pos];
        const float4 c = *(const float4*)(ctx + ((size_t)bei << 8) + (l << 2));
        bf16x4 v;
        v[0] = (__bf16)((float)ov[0] - c.x);
        v[1] = (__bf16)((float)ov[1] - c.y);
        v[2] = (__bf16)((float)ov[2] - c.z);
        v[3] = (__bf16)((float)ov[3] - c.w);
        *(bf16x4*)&mi[wid][it][pos] = v;
    }

    // ---- MFMA over chunk 1 (global k-tiles 8..15) ----
#pragma unroll
    for (int kt = 0; kt < 8; ++kt) {
        const int apos = ((l >> 4) << 6) | (((kt ^ l) & 7) << 3);
        const bf16x8 a0 = *(const bf16x8*)&mi[wid][(l & 15)][apos];
        const bf16x8 a1 = *(const bf16x8*)&mi[wid][16 + (l & 15)][apos];
#pragma unroll
        for (int nt = 0; nt < NT; ++nt) {
            const bf16x8 bb = *(const bf16x8*)(wef + (size_t)((((kt + 8) * NT + nt) << 6) + l) * 8);
            acc[0][nt] = __builtin_amdgcn_mfma_f32_16x16x32_bf16(a0, bb, acc[0][nt], 0, 0, 0);
            acc[1][nt] = __builtin_amdgcn_mfma_f32_16x16x32_bf16(a1, bb, acc[1][nt], 0, 0, 0);
        }
    }

    // ---- epilogue: membrane col (ntile 4, col 0) -> g; write g_n and e_n ----
    const int cgrp = (l >> 4) << 2;
#pragma unroll
    for (int rt = 0; rt < 2; ++rt) {
#pragma unroll
        for (int j = 0; j < 4; ++j) {
            const float m = __shfl(acc[rt][4][j], (l & 48));   // col-64 value of this row group
            const int row = rw0 + rt * 16 + cgrp + j;
            const float mk = mask[row];
            const float gg = mk / (1.f + __expf(-(m + bm)));
            if ((l & 15) == 0) out[row] = gg;
#pragma unroll
            for (int nt = 0; nt < 4; ++nt) {
                out[(size_t)ROWS + ((size_t)row << 6) + (nt << 4) + (l & 15)] =
                    (acc[rt][nt][j] + be4[nt]) * gg;
            }
        }
    }
}

extern "C" void kernel_launch(void* const* d_in, const int* in_sizes, int n_in,
                              void* d_out, int out_size, void* d_ws, size_t ws_size,
                              hipStream_t stream) {
    (void)in_sizes; (void)n_in; (void)out_size; (void)ws_size;
    const float* obs  = (const float*)d_in[0];
    const float* mask = (const float*)d_in[1];
    // d_in[2] = incidence: one-hot of idx, never read (saves 268 MB of traffic)
    const int*   idx  = (const int*)d_in[3];
    const float* w_m  = (const float*)d_in[4];
    const float* b_m  = (const float*)d_in[5];
    const float* w_e  = (const float*)d_in[6];
    const float* b_e  = (const float*)d_in[7];

    char* ws = (char*)d_ws;
    float*    ctx    = (float*)(ws + CTX_OFF);
    __bf16*   wef    = (__bf16*)(ws + WEF_OFF);
    unsigned* hist   = (unsigned*)(ws + HIST_OFF);
    unsigned* cursor = (unsigned*)(ws + CURS_OFF);
    unsigned* order  = (unsigned*)(ws + ORDER_OFF);

    hipMemsetAsync(hist, 0, 2 * BE * sizeof(unsigned), stream);   // hist + cursor contiguous

    wef_kernel<<<(KT * NT * 64 + 255) / 256, 256, 0, stream>>>(w_e, w_m, wef);
    hist_kernel<<<ROWS / 256, 256, 0, stream>>>(idx, hist);
    scan_kernel<<<1, 256, 0, stream>>>(hist, cursor);
    fill_kernel<<<ROWS / 256, 256, 0, stream>>>(idx, cursor, order);
    ctx_kernel<<<BE / 4, 256, 0, stream>>>(obs, hist, cursor, order, ctx);

    fused_kernel<<<ROWS / 128, 256, 0, stream>>>(obs, mask, idx, b_m, b_e, ctx, wef,
                                                 (float*)d_out);
}

// Round 4
// 64.208 us; speedup vs baseline: 8.2425x; 1.0812x over previous
//
#include <hip/hip_runtime.h>

#define B_ 8
#define N_ 8192
#define E_ 1024
#define D_ 256
#define ROWS (B_ * N_)          // 65536
#define BE (B_ * E_)            // 8192
#define K2 512
#define NT 5                    // 64 e-cols + membrane col (+pad to 80 rows of W)
#define KT 16

typedef float  f32x4  __attribute__((ext_vector_type(4)));
typedef __bf16 bf16x8 __attribute__((ext_vector_type(8)));

// ---- workspace layout (bytes) ----
#define CTX_OFF   0                                   // BE*D f32           (8 MB)
#define WEF_OFF   (BE * D_ * 4)                       // frag-packed W bf16 (80 KB)
#define HIST_OFF  (WEF_OFF + KT * NT * 64 * 8 * 2)
#define CURS_OFF  (HIST_OFF + BE * 4)
#define ORDER_OFF (CURS_OFF + BE * 4)                 // + ROWS*4 => ~8.8 MB total

__global__ __launch_bounds__(1024) void zero_kernel(unsigned* __restrict__ p) {
    p[blockIdx.x * 1024 + threadIdx.x] = 0u;          // hist + cursor (16384 u32)
}

// blocks 0..255: histogram of idx. blocks 256..275: pack W fragments.
// wef[((kt*NT+nt)*64 + lane)*8 + i] = W[nt*16 + (lane&15)][kt*32 + (lane>>4)*8 + i]
__global__ __launch_bounds__(256) void histwef_kernel(
    const int* __restrict__ idx, unsigned* __restrict__ hist,
    const float* __restrict__ we, const float* __restrict__ wm,
    __bf16* __restrict__ wef) {
    const int bid = blockIdx.x;
    if (bid < 256) {
        const int row = bid * 256 + threadIdx.x;
        atomicAdd(&hist[((row >> 13) << 10) + idx[row]], 1u);
    } else {
        const int t = (bid - 256) * 256 + threadIdx.x;   // 0..5119
        const int lane = t & 63;
        const int nt = (t >> 6) % NT;
        const int kt = t / (NT * 64);
        const int r  = nt * 16 + (lane & 15);
        const int k0 = kt * 32 + (lane >> 4) * 8;
        bf16x8 v;
#pragma unroll
        for (int i = 0; i < 8; ++i) {
            const float f = (r < 64) ? we[r * K2 + k0 + i]
                                     : ((r == 64) ? wm[k0 + i] : 0.f);
            v[i] = (__bf16)f;
        }
        *(bf16x8*)(wef + (size_t)t * 8) = v;
    }
}

// exclusive scan of hist (8192) -> cursor. One block, shfl-based.
__global__ __launch_bounds__(256) void scan_kernel(const unsigned* __restrict__ hist,
                                                   unsigned* __restrict__ cursor) {
    __shared__ unsigned wsums[4];
    const int t = threadIdx.x;
    unsigned loc[32], s = 0;
#pragma unroll
    for (int i = 0; i < 32; ++i) { loc[i] = hist[t * 32 + i]; s += loc[i]; }
    unsigned inc = s;
#pragma unroll
    for (int off = 1; off < 64; off <<= 1) {
        const unsigned v = __shfl_up(inc, off);
        if ((t & 63) >= off) inc += v;
    }
    if ((t & 63) == 63) wsums[t >> 6] = inc;
    __syncthreads();
    unsigned run = inc - s;
    for (int w = 0; w < (t >> 6); ++w) run += wsums[w];
#pragma unroll
    for (int i = 0; i < 32; ++i) { cursor[t * 32 + i] = run; run += loc[i]; }
}

__global__ __launch_bounds__(256) void fill_kernel(const int* __restrict__ idx,
                                                   unsigned* __restrict__ cursor,
                                                   unsigned* __restrict__ order) {
    const int row = blockIdx.x * 256 + threadIdx.x;
    const int bei = ((row >> 13) << 10) + idx[row];
    order[atomicAdd(&cursor[bei], 1u)] = (unsigned)row;
}

// per-bucket gather-mean; member list broadcast through lanes via shfl
__global__ __launch_bounds__(256) void ctx_kernel(const float* __restrict__ obs,
                                                  const unsigned* __restrict__ hist,
                                                  const unsigned* __restrict__ cursor,
                                                  const unsigned* __restrict__ order,
                                                  float* __restrict__ ctx) {
    const int bucket = blockIdx.x * 4 + (threadIdx.x >> 6);
    const int l = threadIdx.x & 63;
    const unsigned cnt = hist[bucket];
    const unsigned start = cursor[bucket] - cnt;     // cursor = base+cnt after fill
    f32x4 acc = {0.f, 0.f, 0.f, 0.f};
    for (unsigned base = 0; base < cnt; base += 64) {
        const unsigned m = (cnt - base < 64u) ? (cnt - base) : 64u;
        const unsigned myrow = (l < (int)m) ? order[start + base + l] : 0u;
        for (unsigned i = 0; i < m; ++i) {
            const unsigned row = __shfl(myrow, (int)i);
            const f32x4 v = *(const f32x4*)(obs + ((size_t)row << 8) + (l << 2));
            acc += v;
        }
    }
    const float inv = 1.f / fmaxf((float)cnt, 1.f);
    acc *= inv;
    *(f32x4*)(ctx + ((size_t)bucket << 8) + (l << 2)) = acc;
}

// fused GEMM: no LDS. Lane l owns A rows (l&15), 16+(l&15); k-slice (l>>4)*8.
// Each obs fragment loaded once, reused for obs and (obs-ctx) k-halves.
__global__ __launch_bounds__(256) void fused_kernel(
    const float* __restrict__ obs, const float* __restrict__ mask,
    const int* __restrict__ idx, const float* __restrict__ bmp,
    const float* __restrict__ bep, const float* __restrict__ ctx,
    const __bf16* __restrict__ wef, float* __restrict__ out) {

    const int tid = threadIdx.x;
    const int l   = tid & 63;
    const int rw0 = blockIdx.x * 128 + (tid >> 6) * 32;
    const int r0  = rw0 + (l & 15);
    const int r1  = r0 + 16;
    const int q8  = (l >> 4) << 3;      // k-offset within 32-wide tile

    f32x4 acc[2][NT];
#pragma unroll
    for (int a = 0; a < 2; ++a)
#pragma unroll
        for (int b = 0; b < NT; ++b) acc[a][b] = (f32x4){0.f, 0.f, 0.f, 0.f};

    const int bei0 = ((r0 >> 13) << 10) + idx[r0];
    const int bei1 = ((r1 >> 13) << 10) + idx[r1];

    const float* o0 = obs + (((size_t)r0) << 8) + q8;
    const float* o1 = obs + (((size_t)r1) << 8) + q8;
    const float* c0 = ctx + (((size_t)bei0) << 8) + q8;
    const float* c1 = ctx + (((size_t)bei1) << 8) + q8;

#pragma unroll
    for (int g = 0; g < 8; ++g) {
        const f32x4 oa0 = *(const f32x4*)(o0 + g * 32);
        const f32x4 ob0 = *(const f32x4*)(o0 + g * 32 + 4);
        const f32x4 oa1 = *(const f32x4*)(o1 + g * 32);
        const f32x4 ob1 = *(const f32x4*)(o1 + g * 32 + 4);
        const f32x4 ca0 = *(const f32x4*)(c0 + g * 32);
        const f32x4 cb0 = *(const f32x4*)(c0 + g * 32 + 4);
        const f32x4 ca1 = *(const f32x4*)(c1 + g * 32);
        const f32x4 cb1 = *(const f32x4*)(c1 + g * 32 + 4);

        bf16x8 A0, A1, D0, D1;
#pragma unroll
        for (int i = 0; i < 4; ++i) {
            A0[i] = (__bf16)oa0[i];  A0[4 + i] = (__bf16)ob0[i];
            A1[i] = (__bf16)oa1[i];  A1[4 + i] = (__bf16)ob1[i];
            D0[i] = (__bf16)(oa0[i] - ca0[i]);  D0[4 + i] = (__bf16)(ob0[i] - cb0[i]);
            D1[i] = (__bf16)(oa1[i] - ca1[i]);  D1[4 + i] = (__bf16)(ob1[i] - cb1[i]);
        }
#pragma unroll
        for (int nt = 0; nt < NT; ++nt) {
            const bf16x8 bb = *(const bf16x8*)(wef + (size_t)(((g * NT + nt) << 6) + l) * 8);
            acc[0][nt] = __builtin_amdgcn_mfma_f32_16x16x32_bf16(A0, bb, acc[0][nt], 0, 0, 0);
            acc[1][nt] = __builtin_amdgcn_mfma_f32_16x16x32_bf16(A1, bb, acc[1][nt], 0, 0, 0);
        }
#pragma unroll
        for (int nt = 0; nt < NT; ++nt) {
            const bf16x8 bb = *(const bf16x8*)(wef + (size_t)((((8 + g) * NT + nt) << 6) + l) * 8);
            acc[0][nt] = __builtin_amdgcn_mfma_f32_16x16x32_bf16(D0, bb, acc[0][nt], 0, 0, 0);
            acc[1][nt] = __builtin_amdgcn_mfma_f32_16x16x32_bf16(D1, bb, acc[1][nt], 0, 0, 0);
        }
    }

    // epilogue: membrane = ntile 4 col 0 (lives in lane l&48, reg j) -> g_n, e_n
    const float bm = bmp[0];
    float be4[4];
#pragma unroll
    for (int nt = 0; nt < 4; ++nt) be4[nt] = bep[nt * 16 + (l & 15)];

    const int cgrp = (l >> 4) << 2;
#pragma unroll
    for (int rt = 0; rt < 2; ++rt) {
#pragma unroll
        for (int j = 0; j < 4; ++j) {
            const float m  = __shfl(acc[rt][4][j], (l & 48));
            const int row  = rw0 + rt * 16 + cgrp + j;
            const float mk = mask[row];
            const float gg = mk / (1.f + __expf(-(m + bm)));
            if ((l & 15) == 0) out[row] = gg;
#pragma unroll
            for (int nt = 0; nt < 4; ++nt) {
                out[(size_t)ROWS + (((size_t)row) << 6) + (nt << 4) + (l & 15)] =
                    (acc[rt][nt][j] + be4[nt]) * gg;
            }
        }
    }
}

extern "C" void kernel_launch(void* const* d_in, const int* in_sizes, int n_in,
                              void* d_out, int out_size, void* d_ws, size_t ws_size,
                              hipStream_t stream) {
    (void)in_sizes; (void)n_in; (void)out_size; (void)ws_size;
    const float* obs  = (const float*)d_in[0];
    const float* mask = (const float*)d_in[1];
    // d_in[2] = incidence: one-hot of idx, never read (saves 268 MB of traffic)
    const int*   idx  = (const int*)d_in[3];
    const float* w_m  = (const float*)d_in[4];
    const float* b_m  = (const float*)d_in[5];
    const float* w_e  = (const float*)d_in[6];
    const float* b_e  = (const float*)d_in[7];

    char* ws = (char*)d_ws;
    float*    ctx    = (float*)(ws + CTX_OFF);
    __bf16*   wef    = (__bf16*)(ws + WEF_OFF);
    unsigned* hist   = (unsigned*)(ws + HIST_OFF);
    unsigned* cursor = (unsigned*)(ws + CURS_OFF);
    unsigned* order  = (unsigned*)(ws + ORDER_OFF);

    zero_kernel<<<16, 1024, 0, stream>>>(hist);                    // hist+cursor
    histwef_kernel<<<276, 256, 0, stream>>>(idx, hist, w_e, w_m, wef);
    scan_kernel<<<1, 256, 0, stream>>>(hist, cursor);
    fill_kernel<<<ROWS / 256, 256, 0, stream>>>(idx, cursor, order);
    ctx_kernel<<<BE / 4, 256, 0, stream>>>(obs, hist, cursor, order, ctx);
    fused_kernel<<<ROWS / 128, 256, 0, stream>>>(obs, mask, idx, b_m, b_e, ctx, wef,
                                                 (float*)d_out);
}